// Round 11
// baseline (236.469 us; speedup 1.0000x reference)
//
#include <hip/hip_runtime.h>
#include <math.h>

// MoE router: X[8192,4096] fp32 @ W^T -> logits[8192,64] -> top2 softmax scatter.
// d_out = probs[8192*64] ++ routing_map[8192*64] (floats).
// ws: part [4][8192][64] fp32 (8MB). Wb (bf16-split W frags, 1.5MB) in d_out scratch.
//
// R1-R11 (VALU fp32 family, all pinned 92-116us): fp32-FMA floor 27.3us,
//   family capped ~41% duty across 6 structures -> dead end (see git log).
// R12: MFMA bf16 3-limb emulation (6 terms >= 2^-24, err ~1e-7): PASSED,
//   215us total, logits dropped out of top-5 (<78us; top-5 now all 512MB
//   harness ws-poison fills at ~80us = fixed overhead). First structural win.
// R13: two L2-BW fixes. R12's STEP loaded B 6x/step (limb0 x3!) = 24KB/wave
//   /step -> at 4 waves/CU ~103 B/cyc vs ~56 L2 ceiling. (1) load each limb
//   ONCE into bbA/bbB/bbC (12KB/step, loads front-issued); (2) HG 8->4:
//   2 waves/CU -> ~26 B/cyc, under ceiling; part 16->8MB. Floors: X-HBM
//   20.3us, MFMA 12.4us. Predict logits 22-30us, total 150-175us.

#define HDIM 4096
#define NEXP 64
#define NTOK 8192
#define HG 4
#define HSLAB (HDIM / HG)     // 1024 k per block
#define NSTEP (HSLAB / 32)    // 32 K32 steps per block

typedef __attribute__((ext_vector_type(8)))  short    bf16x8;
typedef __attribute__((ext_vector_type(4)))  float    f32x4;
typedef __attribute__((ext_vector_type(4)))  unsigned u32x4;

union AFrag { unsigned u[4]; bf16x8 f; };
union BFrag { u32x4 v;       bf16x8 f; };

// RNE fp32 -> bf16, returned as the masked fp32 bit pattern (top 16 bits).
static __device__ __forceinline__ unsigned rne_mask(float x) {
    unsigned u = __float_as_uint(x);
    return (u + 0x7fffu + ((u >> 16) & 1u)) & 0xffff0000u;
}

#define SSTRIDE ((size_t)128 * 4 * 64 * 4)   // uints per split level

// ---------------- kernel 0: W[64][4096] -> Wb[3][128][4][64][8] bf16 frags ----
__global__ __launch_bounds__(256) void wprep_kernel(
        const float* __restrict__ W, unsigned* __restrict__ Wb) {
    const int kb = blockIdx.x;          // 0..127 (K32 window)
    const int c  = threadIdx.x >> 6;    // col-tile 0..3
    const int l  = threadIdx.x & 63;    // lane
    const int e  = c * 16 + (l & 15);   // expert = B col
    const int k0 = kb * 32 + (l >> 4) * 8;
    const float* src = W + (size_t)e * HDIM + k0;
    float a[8];
    #pragma unroll
    for (int j = 0; j < 8; ++j) a[j] = src[j];
    unsigned m1[8], m2[8], m3[8];
    #pragma unroll
    for (int j = 0; j < 8; ++j) {
        m1[j] = rne_mask(a[j]);
        float r1 = a[j] - __uint_as_float(m1[j]);
        m2[j] = rne_mask(r1);
        float r2 = r1 - __uint_as_float(m2[j]);
        m3[j] = rne_mask(r2);
    }
    size_t base = (((size_t)kb * 4 + c) * 64 + l) * 4;
    #pragma unroll
    for (int q = 0; q < 4; ++q) {
        Wb[0 * SSTRIDE + base + q] = m1[2*q+1] | (m1[2*q] >> 16);
        Wb[1 * SSTRIDE + base + q] = m2[2*q+1] | (m2[2*q] >> 16);
        Wb[2 * SSTRIDE + base + q] = m3[2*q+1] | (m3[2*q] >> 16);
    }
}

// ---------------- kernel 1: partial logits via bf16 MFMA x6 ----------------
#define LOAD_A(BUF, KB)                                                        \
    _Pragma("unroll")                                                          \
    for (int r = 0; r < 4; ++r) {                                              \
        const float* p = Xb + (size_t)(r * 16 + row) * HDIM + (KB) * 32 + kg * 8; \
        *(f32x4*)&BUF[r][0] = *(const f32x4*)p;                                \
        *(f32x4*)&BUF[r][4] = *(const f32x4*)(p + 4);                          \
    }

#define LOAD_B(BB, S, KBG)                                                     \
    _Pragma("unroll")                                                          \
    for (int c = 0; c < 4; ++c)                                                \
        BB[c].v = *(const u32x4*)(Wb + (S) * SSTRIDE +                         \
                                  (((size_t)(KBG) * 4 + c) * 64 + l) * 4);

// split with residual (levels 1,2): FR = bf16 limb, CUR -= limb (exact)
#define SPLIT_R(CUR, FR)                                                       \
    _Pragma("unroll")                                                          \
    for (int r = 0; r < 4; ++r) {                                              \
        unsigned m[8];                                                         \
        _Pragma("unroll")                                                      \
        for (int j = 0; j < 8; ++j) {                                          \
            m[j] = rne_mask(CUR[r][j]);                                        \
            CUR[r][j] -= __uint_as_float(m[j]);                                \
        }                                                                      \
        _Pragma("unroll")                                                      \
        for (int q = 0; q < 4; ++q) FR[r].u[q] = m[2*q+1] | (m[2*q] >> 16);    \
    }

// final split (level 3): no residual needed
#define SPLIT_N(CUR, FR)                                                       \
    _Pragma("unroll")                                                          \
    for (int r = 0; r < 4; ++r) {                                              \
        unsigned m[8];                                                         \
        _Pragma("unroll")                                                      \
        for (int j = 0; j < 8; ++j) m[j] = rne_mask(CUR[r][j]);                \
        _Pragma("unroll")                                                      \
        for (int q = 0; q < 4; ++q) FR[r].u[q] = m[2*q+1] | (m[2*q] >> 16);    \
    }

#define MFMA16(FR, BB)                                                         \
    _Pragma("unroll")                                                          \
    for (int r = 0; r < 4; ++r)                                                \
        _Pragma("unroll")                                                      \
        for (int c = 0; c < 4; ++c)                                            \
            acc[r][c] = __builtin_amdgcn_mfma_f32_16x16x32_bf16(               \
                FR[r].f, BB[c].f, acc[r][c], 0, 0, 0);

// terms: x1(w1,w2,w3) x2(w1,w2) x3(w1); each B limb loaded ONCE per step
#define STEP(CUR, NXT, KB) {                                                   \
    if ((KB) + 1 < NSTEP) { LOAD_A(NXT, (KB) + 1); }                           \
    const int kbg = hg * NSTEP + (KB);                                         \
    LOAD_B(bbA, 0, kbg);                                                       \
    LOAD_B(bbB, 1, kbg);                                                       \
    LOAD_B(bbC, 2, kbg);                                                       \
    SPLIT_R(CUR, fr);            /* fr = x1, CUR = r1 */                       \
    MFMA16(fr, bbA);             /* x1*w1 */                                   \
    MFMA16(fr, bbB);             /* x1*w2 */                                   \
    MFMA16(fr, bbC);             /* x1*w3 */                                   \
    SPLIT_R(CUR, fr);            /* fr = x2, CUR = r2 */                       \
    MFMA16(fr, bbA);             /* x2*w1 */                                   \
    MFMA16(fr, bbB);             /* x2*w2 */                                   \
    SPLIT_N(CUR, fr);            /* fr = x3 */                                 \
    MFMA16(fr, bbA);             /* x3*w1 */                                   \
}

__global__ __launch_bounds__(64) void logits_kernel(
        const float* __restrict__ X, const unsigned* __restrict__ Wb,
        float* __restrict__ part) {
    const int tg  = blockIdx.x >> 2;    // 0..127
    const int hg  = blockIdx.x & 3;     // 0..3
    const int l   = threadIdx.x;        // 0..63
    const int row = l & 15;             // A row / B col within 16-tile
    const int kg  = l >> 4;             // k subgroup 0..3

    const int token0 = tg * 64;
    const int kbase  = hg * HSLAB;

    f32x4 acc[4][4];
    #pragma unroll
    for (int r = 0; r < 4; ++r)
        #pragma unroll
        for (int c = 0; c < 4; ++c) acc[r][c] = (f32x4){0.f, 0.f, 0.f, 0.f};

    const float* Xb = X + (size_t)token0 * HDIM + kbase;

    float s0[4][8], s1[4][8];           // A fp32 staging, named ping-pong
    AFrag fr[4];
    BFrag bbA[4], bbB[4], bbC[4];

    LOAD_A(s0, 0);
    #pragma unroll 1
    for (int n = 0; n < NSTEP; n += 2) {
        STEP(s0, s1, n);
        STEP(s1, s0, n + 1);
    }

    // C/D layout (m89, HW-verified): col = lane&15, row = (lane>>4)*4 + i
    float* dst = part + ((size_t)hg * NTOK + token0) * NEXP;
    #pragma unroll
    for (int r = 0; r < 4; ++r)
        #pragma unroll
        for (int i = 0; i < 4; ++i) {
            int t = r * 16 + kg * 4 + i;
            #pragma unroll
            for (int c = 0; c < 4; ++c)
                dst[(size_t)t * NEXP + c * 16 + row] = acc[r][c][i];
        }
}

// ---------------- kernel 2: reduce HG partials, top-2 softmax, scatter ----------------
__global__ __launch_bounds__(256) void topk_kernel(
        const float* __restrict__ part, float* __restrict__ probs,
        float* __restrict__ rmap) {
    const int wave = threadIdx.x >> 6;
    const int lane = threadIdx.x & 63;       // lane = expert
    const int token = blockIdx.x * 4 + wave;

    const float* p = part + (size_t)token * NEXP + lane;
    float v = 0.f;
    #pragma unroll
    for (int hg = 0; hg < HG; ++hg) v += p[(size_t)hg * NTOK * NEXP];

    // top-1 (lower index wins ties, like lax.top_k)
    float m1 = v; int i1 = lane;
    #pragma unroll
    for (int s = 32; s > 0; s >>= 1) {
        float om = __shfl_xor(m1, s, 64);
        int   oi = __shfl_xor(i1, s, 64);
        if (om > m1 || (om == m1 && oi < i1)) { m1 = om; i1 = oi; }
    }
    // top-2: exclude i1
    float vx = (lane == i1) ? -INFINITY : v;
    float m2 = vx; int i2 = lane;
    #pragma unroll
    for (int s = 32; s > 0; s >>= 1) {
        float om = __shfl_xor(m2, s, 64);
        int   oi = __shfl_xor(i2, s, 64);
        if (om > m2 || (om == m2 && oi < i2)) { m2 = om; i2 = oi; }
    }

    float e2 = expf(m2 - m1);
    float p1 = 1.f / (1.f + e2);
    float p2 = 1.f - p1;

    float prob = (lane == i1) ? p1 : ((lane == i2) ? p2 : 0.f);
    float flag = (lane == i1 || lane == i2) ? 1.f : 0.f;
    probs[(size_t)token * NEXP + lane] = prob;
    rmap [(size_t)token * NEXP + lane] = flag;
}

extern "C" void kernel_launch(void* const* d_in, const int* in_sizes, int n_in,
                              void* d_out, int out_size, void* d_ws, size_t ws_size,
                              hipStream_t stream) {
    const float* X = (const float*)d_in[0];   // [8192,4096]
    const float* W = (const float*)d_in[1];   // [64,4096]
    float* out  = (float*)d_out;
    float* part = (float*)d_ws;               // [4][8192][64] floats = 8MB
    unsigned* Wb = (unsigned*)d_out;          // 1.5MB frag scratch in d_out;
                                              // consumed before topk overwrites.

    wprep_kernel<<<128, 256, 0, stream>>>(W, Wb);
    logits_kernel<<<128 * HG, 64, 0, stream>>>(X, Wb, part);
    topk_kernel<<<NTOK / 4, 256, 0, stream>>>(part, out, out + (size_t)NTOK * NEXP);
}

// Round 12
// 215.923 us; speedup vs baseline: 1.0952x; 1.0952x over previous
//
#include <hip/hip_runtime.h>
#include <math.h>

// MoE router: X[8192,4096] fp32 @ W^T -> logits[8192,64] -> top2 softmax scatter.
// d_out = probs[8192*64] ++ routing_map[8192*64] (floats).
// ws: part [16][8192][64] fp32 (32MB). Wb (bf16-split W frags, 1.5MB) in d_out scratch.
//
// R1-R11 (VALU fp32 family): pinned 92-116us, ~41% duty cap -> dead end.
// R12: MFMA bf16 3-limb emulation (6 terms, err ~1e-7): 215us total, logits
//   ~78us (out of top-5). HG=8: 1024 blocks, 4 waves/CU.
// R13: limb-once B loads + HG=4: REGRESSION 93us logits. Counters: MfmaUtil
//   10.3% (= 9.6us busy ~ 12.4us MFMA floor: matrix work correct), occupancy
//   5.1% (1.6 waves/CU), VALU 15%, HBM 10% -> latency-bound from TLP loss.
//   L2-BW theory falsified (830 GB/s << ceiling). Occupancy is THE lever:
//   2 waves/CU=93us, 4=78us -> extrapolate.
// R14: (1) HG=16: 2048 single-wave blocks = 8/CU = 2 waves/SIMD (VGPR 136
//   <= 256 allows exactly 2/SIMD; LDS 0). part 32MB. (2) truncation split:
//   limb = bits & 0xffff0000 (1 AND vs 4-instr RNE), residual Sterbenz-exact,
//   3 limbs still capture all 24 mantissa bits -> same 2^-24 accuracy, >2x
//   less split-VALU. Predict occupancy 15-22%, MfmaUtil 22-35%, logits
//   35-50us, total 170-190us.

#define HDIM 4096
#define NEXP 64
#define NTOK 8192
#define HG 16
#define HSLAB (HDIM / HG)     // 256 k per block
#define NSTEP (HSLAB / 32)    // 8 K32 steps per block

typedef __attribute__((ext_vector_type(8)))  short    bf16x8;
typedef __attribute__((ext_vector_type(4)))  float    f32x4;
typedef __attribute__((ext_vector_type(4)))  unsigned u32x4;

union AFrag { unsigned u[4]; bf16x8 f; };
union BFrag { u32x4 v;       bf16x8 f; };

// RNE fp32 -> bf16 as masked fp32 bit pattern (wprep only).
static __device__ __forceinline__ unsigned rne_mask(float x) {
    unsigned u = __float_as_uint(x);
    return (u + 0x7fffu + ((u >> 16) & 1u)) & 0xffff0000u;
}

#define SSTRIDE ((size_t)128 * 4 * 64 * 4)   // uints per split level

// ---------------- kernel 0: W[64][4096] -> Wb[3][128][4][64][8] bf16 frags ----
__global__ __launch_bounds__(256) void wprep_kernel(
        const float* __restrict__ W, unsigned* __restrict__ Wb) {
    const int kb = blockIdx.x;          // 0..127 (K32 window)
    const int c  = threadIdx.x >> 6;    // col-tile 0..3
    const int l  = threadIdx.x & 63;    // lane
    const int e  = c * 16 + (l & 15);   // expert = B col
    const int k0 = kb * 32 + (l >> 4) * 8;
    const float* src = W + (size_t)e * HDIM + k0;
    float a[8];
    #pragma unroll
    for (int j = 0; j < 8; ++j) a[j] = src[j];
    unsigned m1[8], m2[8], m3[8];
    #pragma unroll
    for (int j = 0; j < 8; ++j) {
        m1[j] = rne_mask(a[j]);
        float r1 = a[j] - __uint_as_float(m1[j]);
        m2[j] = rne_mask(r1);
        float r2 = r1 - __uint_as_float(m2[j]);
        m3[j] = rne_mask(r2);
    }
    size_t base = (((size_t)kb * 4 + c) * 64 + l) * 4;
    #pragma unroll
    for (int q = 0; q < 4; ++q) {
        Wb[0 * SSTRIDE + base + q] = m1[2*q+1] | (m1[2*q] >> 16);
        Wb[1 * SSTRIDE + base + q] = m2[2*q+1] | (m2[2*q] >> 16);
        Wb[2 * SSTRIDE + base + q] = m3[2*q+1] | (m3[2*q] >> 16);
    }
}

// ---------------- kernel 1: partial logits via bf16 MFMA x6 ----------------
#define LOAD_A(BUF, KB)                                                        \
    _Pragma("unroll")                                                          \
    for (int r = 0; r < 4; ++r) {                                              \
        const float* p = Xb + (size_t)(r * 16 + row) * HDIM + (KB) * 32 + kg * 8; \
        *(f32x4*)&BUF[r][0] = *(const f32x4*)p;                                \
        *(f32x4*)&BUF[r][4] = *(const f32x4*)(p + 4);                          \
    }

#define LOAD_B(BB, S, KBG)                                                     \
    _Pragma("unroll")                                                          \
    for (int c = 0; c < 4; ++c)                                                \
        BB[c].v = *(const u32x4*)(Wb + (S) * SSTRIDE +                         \
                                  (((size_t)(KBG) * 4 + c) * 64 + l) * 4);

// truncation split with residual (levels 1,2): limb = bits&0xffff0000 (1 AND),
// residual x - limb is Sterbenz-exact (same exponent). Pack 2 bf16/u32.
#define SPLIT_R(CUR, FR)                                                       \
    _Pragma("unroll")                                                          \
    for (int r = 0; r < 4; ++r) {                                              \
        unsigned m[8];                                                         \
        _Pragma("unroll")                                                      \
        for (int j = 0; j < 8; ++j) {                                          \
            m[j] = __float_as_uint(CUR[r][j]) & 0xffff0000u;                   \
            CUR[r][j] -= __uint_as_float(m[j]);                                \
        }                                                                      \
        _Pragma("unroll")                                                      \
        for (int q = 0; q < 4; ++q) FR[r].u[q] = m[2*q+1] | (m[2*q] >> 16);    \
    }

// final split (level 3): no residual needed
#define SPLIT_N(CUR, FR)                                                       \
    _Pragma("unroll")                                                          \
    for (int r = 0; r < 4; ++r) {                                              \
        unsigned m[8];                                                         \
        _Pragma("unroll")                                                      \
        for (int j = 0; j < 8; ++j)                                            \
            m[j] = __float_as_uint(CUR[r][j]) & 0xffff0000u;                   \
        _Pragma("unroll")                                                      \
        for (int q = 0; q < 4; ++q) FR[r].u[q] = m[2*q+1] | (m[2*q] >> 16);    \
    }

#define MFMA16(FR, BB)                                                         \
    _Pragma("unroll")                                                          \
    for (int r = 0; r < 4; ++r)                                                \
        _Pragma("unroll")                                                      \
        for (int c = 0; c < 4; ++c)                                            \
            acc[r][c] = __builtin_amdgcn_mfma_f32_16x16x32_bf16(               \
                FR[r].f, BB[c].f, acc[r][c], 0, 0, 0);

// terms: x1(w1,w2,w3) x2(w1,w2) x3(w1); each B limb loaded ONCE per step
#define STEP(CUR, NXT, KB) {                                                   \
    if ((KB) + 1 < NSTEP) { LOAD_A(NXT, (KB) + 1); }                           \
    const int kbg = hg * NSTEP + (KB);                                         \
    LOAD_B(bbA, 0, kbg);                                                       \
    LOAD_B(bbB, 1, kbg);                                                       \
    LOAD_B(bbC, 2, kbg);                                                       \
    SPLIT_R(CUR, fr);            /* fr = x1, CUR = r1 */                       \
    MFMA16(fr, bbA);             /* x1*w1 */                                   \
    MFMA16(fr, bbB);             /* x1*w2 */                                   \
    MFMA16(fr, bbC);             /* x1*w3 */                                   \
    SPLIT_R(CUR, fr);            /* fr = x2, CUR = r2 */                       \
    MFMA16(fr, bbA);             /* x2*w1 */                                   \
    MFMA16(fr, bbB);             /* x2*w2 */                                   \
    SPLIT_N(CUR, fr);            /* fr = x3 */                                 \
    MFMA16(fr, bbA);             /* x3*w1 */                                   \
}

__global__ __launch_bounds__(64) void logits_kernel(
        const float* __restrict__ X, const unsigned* __restrict__ Wb,
        float* __restrict__ part) {
    const int tg  = blockIdx.x >> 4;    // 0..127
    const int hg  = blockIdx.x & 15;    // 0..15
    const int l   = threadIdx.x;        // 0..63
    const int row = l & 15;             // A row / B col within 16-tile
    const int kg  = l >> 4;             // k subgroup 0..3

    const int token0 = tg * 64;
    const int kbase  = hg * HSLAB;

    f32x4 acc[4][4];
    #pragma unroll
    for (int r = 0; r < 4; ++r)
        #pragma unroll
        for (int c = 0; c < 4; ++c) acc[r][c] = (f32x4){0.f, 0.f, 0.f, 0.f};

    const float* Xb = X + (size_t)token0 * HDIM + kbase;

    float s0[4][8], s1[4][8];           // A fp32 staging, named ping-pong
    AFrag fr[4];
    BFrag bbA[4], bbB[4], bbC[4];

    LOAD_A(s0, 0);
    #pragma unroll 1
    for (int n = 0; n < NSTEP; n += 2) {
        STEP(s0, s1, n);
        STEP(s1, s0, n + 1);
    }

    // C/D layout (m89, HW-verified): col = lane&15, row = (lane>>4)*4 + i
    float* dst = part + ((size_t)hg * NTOK + token0) * NEXP;
    #pragma unroll
    for (int r = 0; r < 4; ++r)
        #pragma unroll
        for (int i = 0; i < 4; ++i) {
            int t = r * 16 + kg * 4 + i;
            #pragma unroll
            for (int c = 0; c < 4; ++c)
                dst[(size_t)t * NEXP + c * 16 + row] = acc[r][c][i];
        }
}

// ---------------- kernel 2: reduce HG partials, top-2 softmax, scatter ----------------
__global__ __launch_bounds__(256) void topk_kernel(
        const float* __restrict__ part, float* __restrict__ probs,
        float* __restrict__ rmap) {
    const int wave = threadIdx.x >> 6;
    const int lane = threadIdx.x & 63;       // lane = expert
    const int token = blockIdx.x * 4 + wave;

    const float* p = part + (size_t)token * NEXP + lane;
    float v = 0.f;
    #pragma unroll
    for (int hg = 0; hg < HG; ++hg) v += p[(size_t)hg * NTOK * NEXP];

    // top-1 (lower index wins ties, like lax.top_k)
    float m1 = v; int i1 = lane;
    #pragma unroll
    for (int s = 32; s > 0; s >>= 1) {
        float om = __shfl_xor(m1, s, 64);
        int   oi = __shfl_xor(i1, s, 64);
        if (om > m1 || (om == m1 && oi < i1)) { m1 = om; i1 = oi; }
    }
    // top-2: exclude i1
    float vx = (lane == i1) ? -INFINITY : v;
    float m2 = vx; int i2 = lane;
    #pragma unroll
    for (int s = 32; s > 0; s >>= 1) {
        float om = __shfl_xor(m2, s, 64);
        int   oi = __shfl_xor(i2, s, 64);
        if (om > m2 || (om == m2 && oi < i2)) { m2 = om; i2 = oi; }
    }

    float e2 = expf(m2 - m1);
    float p1 = 1.f / (1.f + e2);
    float p2 = 1.f - p1;

    float prob = (lane == i1) ? p1 : ((lane == i2) ? p2 : 0.f);
    float flag = (lane == i1 || lane == i2) ? 1.f : 0.f;
    probs[(size_t)token * NEXP + lane] = prob;
    rmap [(size_t)token * NEXP + lane] = flag;
}

extern "C" void kernel_launch(void* const* d_in, const int* in_sizes, int n_in,
                              void* d_out, int out_size, void* d_ws, size_t ws_size,
                              hipStream_t stream) {
    const float* X = (const float*)d_in[0];   // [8192,4096]
    const float* W = (const float*)d_in[1];   // [64,4096]
    float* out  = (float*)d_out;
    float* part = (float*)d_ws;               // [16][8192][64] floats = 32MB
    unsigned* Wb = (unsigned*)d_out;          // 1.5MB frag scratch in d_out;
                                              // consumed before topk overwrites.

    wprep_kernel<<<128, 256, 0, stream>>>(W, Wb);
    logits_kernel<<<128 * HG, 64, 0, stream>>>(X, Wb, part);
    topk_kernel<<<NTOK / 4, 256, 0, stream>>>(part, out, out + (size_t)NTOK * NEXP);
}